// Round 1
// baseline (2028.793 us; speedup 1.0000x reference)
//
#include <hip/hip_runtime.h>
#include <cstddef>

#define NM  50000
#define HID 160
#define NEI 8

// ---------------- GEMM: out[m,n] = sum_k A[m,k] * W[n, w_off+k] (+bias[n]) (+addend[m,n])
#define GTM   64
#define APAD  164   // A lds row stride (floats): 16B-aligned rows, 2-way max bank conflict
#define WPAD  84    // W lds row stride (floats): 16B-aligned rows
#define KHALF 80    // stage W in two K-halves to stay under LDS limit

__global__ __launch_bounds__(256) void gemm_k160(
    const float* __restrict__ A,        // [M, 160]
    const float* __restrict__ W,        // rows length w_stride; uses W[n*w_stride + w_off + k]
    int w_off, int w_stride,
    const float* __restrict__ bias,     // [160] or nullptr
    const float* __restrict__ addend,   // [M, 160] or nullptr
    float* __restrict__ out,            // [M, 160]
    int M)
{
    __shared__ float Al[GTM][APAD];
    __shared__ float Wl[HID][WPAD];
    const int t  = threadIdx.x;
    const int m0 = blockIdx.x * GTM;

    // stage A tile: 64 rows x 160 cols (zero-fill tail rows)
    for (int idx = t; idx < GTM * 40; idx += 256) {
        const int m = idx / 40, k4 = (idx % 40) * 4;
        float4 v = make_float4(0.f, 0.f, 0.f, 0.f);
        if (m0 + m < M)
            v = *reinterpret_cast<const float4*>(&A[(size_t)(m0 + m) * HID + k4]);
        *reinterpret_cast<float4*>(&Al[m][k4]) = v;
    }

    const int c  = t & 15;          // column base: n = c + 16*j  (coalesced stores)
    const int mb = (t >> 4) << 2;   // row base: 4 rows per thread

    float acc[4][10];
    #pragma unroll
    for (int i = 0; i < 4; ++i)
        #pragma unroll
        for (int j = 0; j < 10; ++j) acc[i][j] = 0.f;

    for (int kh = 0; kh < 2; ++kh) {
        __syncthreads();
        // stage W half: 160 rows x 80 k-cols
        for (int idx = t; idx < HID * 20; idx += 256) {
            const int n = idx / 20, k4 = (idx % 20) * 4;
            const float4 wv = *reinterpret_cast<const float4*>(
                &W[(size_t)n * w_stride + w_off + kh * KHALF + k4]);
            *reinterpret_cast<float4*>(&Wl[n][k4]) = wv;
        }
        __syncthreads();

        #pragma unroll 4
        for (int k4 = 0; k4 < KHALF; k4 += 4) {
            float4 a[4];
            #pragma unroll
            for (int i = 0; i < 4; ++i)
                a[i] = *reinterpret_cast<const float4*>(&Al[mb + i][kh * KHALF + k4]);
            #pragma unroll
            for (int j = 0; j < 10; ++j) {
                const float4 w = *reinterpret_cast<const float4*>(&Wl[c + 16 * j][k4]);
                #pragma unroll
                for (int i = 0; i < 4; ++i) {
                    acc[i][j] = fmaf(a[i].x, w.x, acc[i][j]);
                    acc[i][j] = fmaf(a[i].y, w.y, acc[i][j]);
                    acc[i][j] = fmaf(a[i].z, w.z, acc[i][j]);
                    acc[i][j] = fmaf(a[i].w, w.w, acc[i][j]);
                }
            }
        }
    }

    #pragma unroll
    for (int j = 0; j < 10; ++j) {
        const int n = c + 16 * j;
        const float b = bias ? bias[n] : 0.f;
        #pragma unroll
        for (int i = 0; i < 4; ++i) {
            const int m = m0 + mb + i;
            if (m < M) {
                float v = acc[i][j] + b;
                if (addend) v += addend[(size_t)m * HID + n];
                out[(size_t)m * HID + n] = v;
            }
        }
    }
}

// ---------------- gather: sum_h[n] = sum_k h[g]; sgh[n] = sum_k sigmoid(xr[n]+hU[g]) * h[g]
__global__ __launch_bounds__(320) void gather_kernel(
    const float* __restrict__ hcur,   // [N,160]
    const float* __restrict__ hU,     // [N,160] = h @ Ur^T + Ur_b
    const float* __restrict__ xr,     // [N,160] = x @ Wr^T
    const int*   __restrict__ graph,  // [N,8]
    float* __restrict__ sumh,         // [N,160]
    float* __restrict__ sgh)          // [N,160]
{
    __shared__ int gsh[8][NEI];
    const int t = threadIdx.x;
    if (t < 64) {
        const int n = blockIdx.x * 8 + (t >> 3);
        gsh[t >> 3][t & 7] = graph[(size_t)n * NEI + (t & 7)];
    }
    __syncthreads();

    const int nl = t / 40;
    const int n  = blockIdx.x * 8 + nl;
    const int c4 = (t % 40) * 4;

    const float4 x4 = *reinterpret_cast<const float4*>(&xr[(size_t)n * HID + c4]);
    float sx = 0.f, sy = 0.f, sz = 0.f, sw = 0.f;
    float gx = 0.f, gy = 0.f, gz = 0.f, gw = 0.f;

    #pragma unroll
    for (int k = 0; k < NEI; ++k) {
        const int g = gsh[nl][k];
        const float4 hv = *reinterpret_cast<const float4*>(&hcur[(size_t)g * HID + c4]);
        const float4 hu = *reinterpret_cast<const float4*>(&hU  [(size_t)g * HID + c4]);
        const float rx = 1.f / (1.f + __expf(-(x4.x + hu.x)));
        const float ry = 1.f / (1.f + __expf(-(x4.y + hu.y)));
        const float rz = 1.f / (1.f + __expf(-(x4.z + hu.z)));
        const float rw = 1.f / (1.f + __expf(-(x4.w + hu.w)));
        sx += hv.x; sy += hv.y; sz += hv.z; sw += hv.w;
        gx = fmaf(rx, hv.x, gx);
        gy = fmaf(ry, hv.y, gy);
        gz = fmaf(rz, hv.z, gz);
        gw = fmaf(rw, hv.w, gw);
    }
    float4 so = make_float4(sx, sy, sz, sw);
    float4 go = make_float4(gx, gy, gz, gw);
    *reinterpret_cast<float4*>(&sumh[(size_t)n * HID + c4]) = so;
    *reinterpret_cast<float4*>(&sgh [(size_t)n * HID + c4]) = go;
}

// ---------------- update: h = ((1-z)*sum_h + z*tanh(hlin)) * mask
__device__ __forceinline__ float sigf(float v) { return 1.f / (1.f + __expf(-v)); }
__device__ __forceinline__ float tanhfast(float v) { return 2.f / (1.f + __expf(-2.f * v)) - 1.f; }

__global__ __launch_bounds__(256) void update_kernel(
    const float* __restrict__ zlin,
    const float* __restrict__ hlin,
    const float* __restrict__ sumh,
    float* __restrict__ out)
{
    const int idx = blockIdx.x * 256 + threadIdx.x;  // float4 index
    if (idx >= NM * 40) return;
    const int row = idx / 40;

    const float4 zl = reinterpret_cast<const float4*>(zlin)[idx];
    const float4 hl = reinterpret_cast<const float4*>(hlin)[idx];
    const float4 sh = reinterpret_cast<const float4*>(sumh)[idx];

    float4 o;
    {
        const float z = sigf(zl.x), p = tanhfast(hl.x);
        o.x = (1.f - z) * sh.x + z * p;
    }
    {
        const float z = sigf(zl.y), p = tanhfast(hl.y);
        o.y = (1.f - z) * sh.y + z * p;
    }
    {
        const float z = sigf(zl.z), p = tanhfast(hl.z);
        o.z = (1.f - z) * sh.z + z * p;
    }
    {
        const float z = sigf(zl.w), p = tanhfast(hl.w);
        o.w = (1.f - z) * sh.w + z * p;
    }
    if (row == 0) o = make_float4(0.f, 0.f, 0.f, 0.f);
    reinterpret_cast<float4*>(out)[idx] = o;
}

extern "C" void kernel_launch(void* const* d_in, const int* in_sizes, int n_in,
                              void* d_out, int out_size, void* d_ws, size_t ws_size,
                              hipStream_t stream)
{
    const float* h0   = (const float*)d_in[0];
    const float* x    = (const float*)d_in[1];
    const int*   grf  = (const int*)  d_in[2];
    const float* Wz_w = (const float*)d_in[3];
    const float* Wz_b = (const float*)d_in[4];
    const float* Wr_w = (const float*)d_in[5];
    const float* Ur_w = (const float*)d_in[6];
    const float* Ur_b = (const float*)d_in[7];
    const float* Wh_w = (const float*)d_in[8];
    const float* Wh_b = (const float*)d_in[9];
    float* out = (float*)d_out;

    const size_t per = (size_t)NM * HID;
    float* ws   = (float*)d_ws;
    float* xz   = ws + 0 * per;   // x @ Wzx^T + Wz_b   (persistent)
    float* xr   = ws + 1 * per;   // x @ Wr^T           (persistent)
    float* xh   = ws + 2 * per;   // x @ Whx^T + Wh_b   (persistent)
    float* hU   = ws + 3 * per;   // h @ Ur^T + Ur_b ; reused as zlin
    float* sumh = ws + 4 * per;
    float* sgh  = ws + 5 * per;   // reused in-place as hlin
    float* zlin = hU;
    float* hlin = sgh;

    const dim3 gb((NM + GTM - 1) / GTM), gt(256);   // 782 blocks
    const dim3 sb(NM / 8), st(320);                 // 6250 blocks
    const dim3 ub((NM * 40 + 255) / 256), ut(256);  // 7813 blocks

    // precompute loop-invariant x-projections
    gemm_k160<<<gb, gt, 0, stream>>>(x, Wz_w, 0, 2 * HID, Wz_b, nullptr, xz, NM);
    gemm_k160<<<gb, gt, 0, stream>>>(x, Wr_w, 0, HID,     nullptr, nullptr, xr, NM);
    gemm_k160<<<gb, gt, 0, stream>>>(x, Wh_w, 0, 2 * HID, Wh_b, nullptr, xh, NM);

    const float* hcur = h0;
    for (int it = 0; it < 3; ++it) {
        // hU = h @ Ur^T + Ur_b   (replaces the nkh,gh->nkg einsum via gather)
        gemm_k160<<<gb, gt, 0, stream>>>(hcur, Ur_w, 0, HID, Ur_b, nullptr, hU, NM);
        gather_kernel<<<sb, st, 0, stream>>>(hcur, hU, xr, grf, sumh, sgh);
        // zlin = sum_h @ Wzh^T + xz ; hlin = sgh @ Whh^T + xh (in place over sgh)
        gemm_k160<<<gb, gt, 0, stream>>>(sumh, Wz_w, HID, 2 * HID, nullptr, xz, zlin, NM);
        gemm_k160<<<gb, gt, 0, stream>>>(sgh,  Wh_w, HID, 2 * HID, nullptr, xh, hlin, NM);
        update_kernel<<<ub, ut, 0, stream>>>(zlin, hlin, sumh, out);
        hcur = out;
    }
}

// Round 2
// 973.695 us; speedup vs baseline: 2.0836x; 2.0836x over previous
//
#include <hip/hip_runtime.h>
#include <cstddef>
#include <cstdint>

#define NM  50000
#define HID 160
#define NEI 8

typedef __attribute__((ext_vector_type(8))) short  short8;
typedef __attribute__((ext_vector_type(4))) float  f32x4;

__device__ __forceinline__ ushort f2bf(float f) {
    union { float f; uint32_t u; } v; v.f = f;
    const uint32_t r = v.u + 0x7fffu + ((v.u >> 16) & 1u);   // RNE
    return (ushort)(r >> 16);
}
__device__ __forceinline__ float bf2f(ushort h) {
    union { uint32_t u; float f; } v; v.u = ((uint32_t)h) << 16;
    return v.f;
}

// ---------------- weight pre-pack: 6 blocks of [160n][160k] -> frag-linear
// layout per block: [nt(10)][ks(5)][lane(64)] x short8 ; hi then lo (+25600 ushort)
__global__ __launch_bounds__(256) void pack_weights(
    const float* __restrict__ Wz, const float* __restrict__ Wr,
    const float* __restrict__ Ur, const float* __restrict__ Wh,
    ushort* __restrict__ dst)
{
    const float* src; int off, stride;
    switch (blockIdx.x) {
        case 0:  src = Wz; off = 0;   stride = 320; break;  // Wzx
        case 1:  src = Wz; off = 160; stride = 320; break;  // Wzh
        case 2:  src = Wr; off = 0;   stride = 160; break;  // Wrx
        case 3:  src = Ur; off = 0;   stride = 160; break;  // Ur
        case 4:  src = Wh; off = 0;   stride = 320; break;  // Whx
        default: src = Wh; off = 160; stride = 320; break;  // Whh
    }
    ushort* hi = dst + (size_t)blockIdx.x * 51200;
    ushort* lo = hi + 25600;
    const int t = threadIdx.x, l = t & 63;
    for (int tile = t >> 6; tile < 50; tile += 4) {
        const int nt = tile / 5, ks = tile % 5;
        const int n = nt * 16 + (l & 15);
        const int k = ks * 32 + (l >> 4) * 8;
        const float* s = &src[(size_t)n * stride + off + k];
        const size_t o = ((size_t)tile * 64 + l) * 8;
        #pragma unroll
        for (int j = 0; j < 8; ++j) {
            const float a  = s[j];
            const ushort hb = f2bf(a);
            hi[o + j] = hb;
            lo[o + j] = f2bf(a - bf2f(hb));
        }
    }
}

// ---------------- GEMM: out[m,n] = sum_k A[m,k]*W[n,k] (+bias[n]) (+addend[m,n])
// split-bf16 MFMA: A=Ah+Al, W=Wh+Wl; acc += Ah*Wh + Ah*Wl + Al*Wh
#define AST 168   // LDS row stride (bf16): 336B -> conflict-benign b128 reads

__global__ __launch_bounds__(256) void gemm_mfma(
    const float* __restrict__ A,
    const ushort* __restrict__ wp,      // hi frags; lo at wp+25600
    const float* __restrict__ bias,     // [160] or nullptr
    const float* __restrict__ addend,   // [M,160] or nullptr
    float* __restrict__ out, int M)
{
    __shared__ ushort Ahs[64 * AST];
    __shared__ ushort Als[64 * AST];
    const int t  = threadIdx.x;
    const int m0 = blockIdx.x * 64;

    // stage A tile, converting f32 -> hi/lo bf16 (coalesced float4 reads)
    for (int idx = t; idx < 64 * 40; idx += 256) {
        const int m = idx / 40, k4 = (idx % 40) * 4;
        float4 v = make_float4(0.f, 0.f, 0.f, 0.f);
        if (m0 + m < M) v = *reinterpret_cast<const float4*>(&A[(size_t)(m0 + m) * HID + k4]);
        ushort4 h, lo;
        h.x = f2bf(v.x); lo.x = f2bf(v.x - bf2f(h.x));
        h.y = f2bf(v.y); lo.y = f2bf(v.y - bf2f(h.y));
        h.z = f2bf(v.z); lo.z = f2bf(v.z - bf2f(h.z));
        h.w = f2bf(v.w); lo.w = f2bf(v.w - bf2f(h.w));
        *reinterpret_cast<ushort4*>(&Ahs[m * AST + k4]) = h;
        *reinterpret_cast<ushort4*>(&Als[m * AST + k4]) = lo;
    }
    __syncthreads();

    const int w  = t >> 6, l = t & 63;
    const int ar = (w << 4) + (l & 15);     // A-frag row
    const int kg = (l >> 4) << 3;           // A/B-frag k base within k-step

    f32x4 acc[10];
    #pragma unroll
    for (int nt = 0; nt < 10; ++nt) acc[nt] = (f32x4){0.f, 0.f, 0.f, 0.f};

    const short8* WH = reinterpret_cast<const short8*>(wp);
    const short8* WL = reinterpret_cast<const short8*>(wp + 25600);

    #pragma unroll
    for (int ks = 0; ks < 5; ++ks) {
        const short8 ah = *reinterpret_cast<const short8*>(&Ahs[ar * AST + ks * 32 + kg]);
        const short8 al = *reinterpret_cast<const short8*>(&Als[ar * AST + ks * 32 + kg]);
        #pragma unroll
        for (int nt = 0; nt < 10; ++nt) {
            const short8 bh = WH[(nt * 5 + ks) * 64 + l];
            const short8 bl = WL[(nt * 5 + ks) * 64 + l];
            acc[nt] = __builtin_amdgcn_mfma_f32_16x16x32_bf16(ah, bh, acc[nt], 0, 0, 0);
            acc[nt] = __builtin_amdgcn_mfma_f32_16x16x32_bf16(ah, bl, acc[nt], 0, 0, 0);
            acc[nt] = __builtin_amdgcn_mfma_f32_16x16x32_bf16(al, bh, acc[nt], 0, 0, 0);
        }
    }

    // epilogue: C/D layout col=l&15, row=(l>>4)*4+reg
    const int r0 = m0 + (w << 4) + ((l >> 4) << 2);
    const int cb = l & 15;
    #pragma unroll
    for (int nt = 0; nt < 10; ++nt) {
        const int col = nt * 16 + cb;
        const float b = bias ? bias[col] : 0.f;
        #pragma unroll
        for (int r = 0; r < 4; ++r) {
            const int m = r0 + r;
            if (m < M) {
                float v = acc[nt][r] + b;
                if (addend) v += addend[(size_t)m * HID + col];
                out[(size_t)m * HID + col] = v;
            }
        }
    }
}

// ---------------- gather: sum_h = sum_k h[g]; sgh = sum_k sigmoid(xr+hU[g]) * h[g]
__global__ __launch_bounds__(320) void gather_kernel(
    const float* __restrict__ hcur, const float* __restrict__ hU,
    const float* __restrict__ xr,   const int* __restrict__ graph,
    float* __restrict__ sumh, float* __restrict__ sgh)
{
    __shared__ int gsh[8][NEI];
    const int t = threadIdx.x;
    if (t < 64) {
        const int n = blockIdx.x * 8 + (t >> 3);
        gsh[t >> 3][t & 7] = graph[(size_t)n * NEI + (t & 7)];
    }
    __syncthreads();

    const int nl = t / 40;
    const int n  = blockIdx.x * 8 + nl;
    const int c4 = (t % 40) * 4;

    const float4 x4 = *reinterpret_cast<const float4*>(&xr[(size_t)n * HID + c4]);
    float sx = 0.f, sy = 0.f, sz = 0.f, sw = 0.f;
    float gx = 0.f, gy = 0.f, gz = 0.f, gw = 0.f;

    #pragma unroll
    for (int k = 0; k < NEI; ++k) {
        const int g = gsh[nl][k];
        const float4 hv = *reinterpret_cast<const float4*>(&hcur[(size_t)g * HID + c4]);
        const float4 hu = *reinterpret_cast<const float4*>(&hU  [(size_t)g * HID + c4]);
        const float rx = 1.f / (1.f + __expf(-(x4.x + hu.x)));
        const float ry = 1.f / (1.f + __expf(-(x4.y + hu.y)));
        const float rz = 1.f / (1.f + __expf(-(x4.z + hu.z)));
        const float rw = 1.f / (1.f + __expf(-(x4.w + hu.w)));
        sx += hv.x; sy += hv.y; sz += hv.z; sw += hv.w;
        gx = fmaf(rx, hv.x, gx);
        gy = fmaf(ry, hv.y, gy);
        gz = fmaf(rz, hv.z, gz);
        gw = fmaf(rw, hv.w, gw);
    }
    *reinterpret_cast<float4*>(&sumh[(size_t)n * HID + c4]) = make_float4(sx, sy, sz, sw);
    *reinterpret_cast<float4*>(&sgh [(size_t)n * HID + c4]) = make_float4(gx, gy, gz, gw);
}

// ---------------- update: h = ((1-z)*sum_h + z*tanh(hlin)) * mask
__device__ __forceinline__ float sigf(float v)     { return 1.f / (1.f + __expf(-v)); }
__device__ __forceinline__ float tanhfast(float v) { return 2.f / (1.f + __expf(-2.f * v)) - 1.f; }

__global__ __launch_bounds__(256) void update_kernel(
    const float* __restrict__ zlin, const float* __restrict__ hlin,
    const float* __restrict__ sumh, float* __restrict__ out)
{
    const int idx = blockIdx.x * 256 + threadIdx.x;   // float4 index
    if (idx >= NM * 40) return;
    const int row = idx / 40;

    const float4 zl = reinterpret_cast<const float4*>(zlin)[idx];
    const float4 hl = reinterpret_cast<const float4*>(hlin)[idx];
    const float4 sh = reinterpret_cast<const float4*>(sumh)[idx];

    float4 o;
    { const float z = sigf(zl.x), p = tanhfast(hl.x); o.x = (1.f - z) * sh.x + z * p; }
    { const float z = sigf(zl.y), p = tanhfast(hl.y); o.y = (1.f - z) * sh.y + z * p; }
    { const float z = sigf(zl.z), p = tanhfast(hl.z); o.z = (1.f - z) * sh.z + z * p; }
    { const float z = sigf(zl.w), p = tanhfast(hl.w); o.w = (1.f - z) * sh.w + z * p; }
    if (row == 0) o = make_float4(0.f, 0.f, 0.f, 0.f);
    reinterpret_cast<float4*>(out)[idx] = o;
}

extern "C" void kernel_launch(void* const* d_in, const int* in_sizes, int n_in,
                              void* d_out, int out_size, void* d_ws, size_t ws_size,
                              hipStream_t stream)
{
    const float* h0   = (const float*)d_in[0];
    const float* x    = (const float*)d_in[1];
    const int*   grf  = (const int*)  d_in[2];
    const float* Wz_w = (const float*)d_in[3];
    const float* Wz_b = (const float*)d_in[4];
    const float* Wr_w = (const float*)d_in[5];
    const float* Ur_w = (const float*)d_in[6];
    const float* Ur_b = (const float*)d_in[7];
    const float* Wh_w = (const float*)d_in[8];
    const float* Wh_b = (const float*)d_in[9];
    float* out = (float*)d_out;

    const size_t per = (size_t)NM * HID;
    float* ws   = (float*)d_ws;
    float* xz   = ws + 0 * per;
    float* xr   = ws + 1 * per;
    float* xh   = ws + 2 * per;
    float* hU   = ws + 3 * per;   // reused as zlin
    float* sumh = ws + 4 * per;
    float* sgh  = ws + 5 * per;   // reused in-place as hlin
    float* zlin = hU;
    float* hlin = sgh;
    ushort* wpack = (ushort*)(ws + 6 * per);   // 6 x 51200 ushorts
    #define WP(i) (wpack + (size_t)(i) * 51200)

    const dim3 gb((NM + 63) / 64), gt(256);          // 782 blocks
    const dim3 sb(NM / 8), st(320);
    const dim3 ub((NM * 40 + 255) / 256), ut(256);

    pack_weights<<<6, 256, 0, stream>>>(Wz_w, Wr_w, Ur_w, Wh_w, wpack);

    // loop-invariant x projections
    gemm_mfma<<<gb, gt, 0, stream>>>(x, WP(0), Wz_b, nullptr, xz, NM);
    gemm_mfma<<<gb, gt, 0, stream>>>(x, WP(2), nullptr, nullptr, xr, NM);
    gemm_mfma<<<gb, gt, 0, stream>>>(x, WP(4), Wh_b, nullptr, xh, NM);

    const float* hcur = h0;
    for (int it = 0; it < 3; ++it) {
        gemm_mfma<<<gb, gt, 0, stream>>>(hcur, WP(3), Ur_b, nullptr, hU, NM);
        gather_kernel<<<sb, st, 0, stream>>>(hcur, hU, xr, grf, sumh, sgh);
        gemm_mfma<<<gb, gt, 0, stream>>>(sumh, WP(1), nullptr, xz, zlin, NM);
        gemm_mfma<<<gb, gt, 0, stream>>>(sgh,  WP(5), nullptr, xh, hlin, NM);
        update_kernel<<<ub, ut, 0, stream>>>(zlin, hlin, sumh, out);
        hcur = out;
    }
}

// Round 3
// 642.823 us; speedup vs baseline: 3.1561x; 1.5147x over previous
//
#include <hip/hip_runtime.h>
#include <cstddef>
#include <cstdint>

#define NM  50000
#define HID 160
#define NEI 8
#define AST 168   // LDS row stride (ushorts): 336B rows, conflict-benign b128 reads

// packed-weight offsets (ushort units)
#define WPX_HI   0        // [30nt][5ks][64l][8] x-proj weights (Wzx,Wrx,Whx)
#define WPX_LO   76800
#define WPU_BASE 153600   // Ur   hi, lo at +25600
#define WPZH_BASE 204800  // Wzh  hi, lo at +25600
#define WPHH_BASE 256000  // Whh  hi, lo at +25600
#define WPACK_TOTAL 307200

typedef __attribute__((ext_vector_type(8))) short  short8;
typedef __attribute__((ext_vector_type(4))) float  f32x4;

__device__ __forceinline__ ushort f2bf(float f) {
    union { float f; uint32_t u; } v; v.f = f;
    const uint32_t r = v.u + 0x7fffu + ((v.u >> 16) & 1u);   // RNE
    return (ushort)(r >> 16);
}
__device__ __forceinline__ float bf2f(ushort h) {
    union { uint32_t u; float f; } v; v.u = ((uint32_t)h) << 16;
    return v.f;
}
__device__ __forceinline__ float sigf(float v)     { return 1.f / (1.f + __expf(-v)); }
__device__ __forceinline__ float tanhfast(float v) { return 2.f / (1.f + __expf(-2.f * v)) - 1.f; }

// ---------------- weight pre-pack into MFMA B-fragment-linear order (hi/lo bf16)
__global__ __launch_bounds__(256) void pack_weights(
    const float* __restrict__ Wz, const float* __restrict__ Wr,
    const float* __restrict__ Ur, const float* __restrict__ Wh,
    ushort* __restrict__ dst)
{
    const float* src; int off, stride, ntb = 0; ushort *hi, *lo;
    switch (blockIdx.x) {
        case 0:  src = Wz; off = 0;   stride = 320; hi = dst + WPX_HI;   lo = dst + WPX_LO;  ntb = 0;  break;
        case 1:  src = Wr; off = 0;   stride = 160; hi = dst + WPX_HI;   lo = dst + WPX_LO;  ntb = 10; break;
        case 2:  src = Wh; off = 0;   stride = 320; hi = dst + WPX_HI;   lo = dst + WPX_LO;  ntb = 20; break;
        case 3:  src = Ur; off = 0;   stride = 160; hi = dst + WPU_BASE; lo = hi + 25600;    break;
        case 4:  src = Wz; off = 160; stride = 320; hi = dst + WPZH_BASE;lo = hi + 25600;    break;
        default: src = Wh; off = 160; stride = 320; hi = dst + WPHH_BASE;lo = hi + 25600;    break;
    }
    const int t = threadIdx.x, l = t & 63;
    for (int tile = t >> 6; tile < 50; tile += 4) {
        const int ntl = tile / 5, ks = tile % 5;
        const int n = ntl * 16 + (l & 15);           // local W row
        const int k = ks * 32 + (l >> 4) * 8;
        const float* s = &src[(size_t)n * stride + off + k];
        const size_t o = ((size_t)((ntb + ntl) * 5 + ks) * 64 + l) * 8;
        #pragma unroll
        for (int j = 0; j < 8; ++j) {
            const float a  = s[j];
            const ushort hb = f2bf(a);
            hi[o + j] = hb;
            lo[o + j] = f2bf(a - bf2f(hb));
        }
    }
}

// ---------------- x projections: xproj[m, 0:160]=x@Wzx^T+Wz_b ; [160:320]=x@Wr^T ; [320:480]=x@Whx^T+Wh_b
__global__ __launch_bounds__(256) void xproj_gemm(
    const float* __restrict__ x, const ushort* __restrict__ wpack,
    const float* __restrict__ Wz_b, const float* __restrict__ Wh_b,
    ushort* __restrict__ xproj, int M)
{
    __shared__ ushort Ah[64 * AST];
    __shared__ ushort Al[64 * AST];
    const int t = threadIdx.x, m0 = blockIdx.x * 64;

    for (int idx = t; idx < 64 * 40; idx += 256) {
        const int m = idx / 40, k4 = (idx % 40) * 4;
        float4 v = make_float4(0.f, 0.f, 0.f, 0.f);
        if (m0 + m < M) v = *reinterpret_cast<const float4*>(&x[(size_t)(m0 + m) * HID + k4]);
        ushort4 h, lo;
        h.x = f2bf(v.x); lo.x = f2bf(v.x - bf2f(h.x));
        h.y = f2bf(v.y); lo.y = f2bf(v.y - bf2f(h.y));
        h.z = f2bf(v.z); lo.z = f2bf(v.z - bf2f(h.z));
        h.w = f2bf(v.w); lo.w = f2bf(v.w - bf2f(h.w));
        *reinterpret_cast<ushort4*>(&Ah[m * AST + k4]) = h;
        *reinterpret_cast<ushort4*>(&Al[m * AST + k4]) = lo;
    }
    __syncthreads();

    const int w = t >> 6, l = t & 63;
    const int ar = (w << 4) + (l & 15);
    const int kg = (l >> 4) << 3;

    f32x4 acc[30];
    #pragma unroll
    for (int nt = 0; nt < 30; ++nt) acc[nt] = (f32x4){0.f, 0.f, 0.f, 0.f};

    const short8* WH = reinterpret_cast<const short8*>(wpack + WPX_HI);
    const short8* WL = reinterpret_cast<const short8*>(wpack + WPX_LO);

    for (int ks = 0; ks < 5; ++ks) {
        const short8 ah = *reinterpret_cast<const short8*>(&Ah[ar * AST + ks * 32 + kg]);
        const short8 al = *reinterpret_cast<const short8*>(&Al[ar * AST + ks * 32 + kg]);
        #pragma unroll
        for (int nt = 0; nt < 30; ++nt) {
            const short8 bh = WH[(nt * 5 + ks) * 64 + l];
            const short8 bl = WL[(nt * 5 + ks) * 64 + l];
            acc[nt] = __builtin_amdgcn_mfma_f32_16x16x32_bf16(ah, bh, acc[nt], 0, 0, 0);
            acc[nt] = __builtin_amdgcn_mfma_f32_16x16x32_bf16(ah, bl, acc[nt], 0, 0, 0);
            acc[nt] = __builtin_amdgcn_mfma_f32_16x16x32_bf16(al, bh, acc[nt], 0, 0, 0);
        }
    }

    const int r0 = m0 + (w << 4) + ((l >> 4) << 2);
    const int cb = l & 15;
    #pragma unroll
    for (int nt = 0; nt < 30; ++nt) {
        const int col = nt * 16 + cb;   // global col in [0,480)
        float b = 0.f;
        if (col < 160)      b = Wz_b[col];
        else if (col >= 320) b = Wh_b[col - 320];
        #pragma unroll
        for (int r = 0; r < 4; ++r) {
            const int m = r0 + r;
            if (m < M) xproj[(size_t)m * 480 + col] = f2bf(acc[nt][r] + b);
        }
    }
}

// ---------------- hU = bf16(h @ Ur^T + Ur_b) ; A staged bf16-only, W split (2 MFMA)
__global__ __launch_bounds__(256, 3) void gemm_hU(
    const float* __restrict__ h, const ushort* __restrict__ wpack,
    const float* __restrict__ Ur_b, ushort* __restrict__ hUb, int M)
{
    __shared__ ushort As[64 * AST];
    const int t = threadIdx.x, m0 = blockIdx.x * 64;

    for (int idx = t; idx < 64 * 40; idx += 256) {
        const int m = idx / 40, k4 = (idx % 40) * 4;
        float4 v = make_float4(0.f, 0.f, 0.f, 0.f);
        if (m0 + m < M) v = *reinterpret_cast<const float4*>(&h[(size_t)(m0 + m) * HID + k4]);
        ushort4 hv;
        hv.x = f2bf(v.x); hv.y = f2bf(v.y); hv.z = f2bf(v.z); hv.w = f2bf(v.w);
        *reinterpret_cast<ushort4*>(&As[m * AST + k4]) = hv;
    }
    __syncthreads();

    const int w = t >> 6, l = t & 63;
    const int ar = (w << 4) + (l & 15);
    const int kg = (l >> 4) << 3;

    f32x4 acc[10];
    #pragma unroll
    for (int nt = 0; nt < 10; ++nt) acc[nt] = (f32x4){0.f, 0.f, 0.f, 0.f};

    const short8* WH = reinterpret_cast<const short8*>(wpack + WPU_BASE);
    const short8* WL = reinterpret_cast<const short8*>(wpack + WPU_BASE + 25600);

    #pragma unroll
    for (int ks = 0; ks < 5; ++ks) {
        const short8 a = *reinterpret_cast<const short8*>(&As[ar * AST + ks * 32 + kg]);
        #pragma unroll
        for (int nt = 0; nt < 10; ++nt) {
            const short8 bh = WH[(nt * 5 + ks) * 64 + l];
            const short8 bl = WL[(nt * 5 + ks) * 64 + l];
            acc[nt] = __builtin_amdgcn_mfma_f32_16x16x32_bf16(a, bh, acc[nt], 0, 0, 0);
            acc[nt] = __builtin_amdgcn_mfma_f32_16x16x32_bf16(a, bl, acc[nt], 0, 0, 0);
        }
    }

    const int r0 = m0 + (w << 4) + ((l >> 4) << 2);
    const int cb = l & 15;
    #pragma unroll
    for (int nt = 0; nt < 10; ++nt) {
        const int col = nt * 16 + cb;
        const float b = Ur_b[col];
        #pragma unroll
        for (int r = 0; r < 4; ++r) {
            const int m = r0 + r;
            if (m < M) hUb[(size_t)m * HID + col] = f2bf(acc[nt][r] + b);
        }
    }
}

// ---------------- gather: sumh(f32) = sum h[g]; sgh(bf16) = sum sigmoid(xr+hU[g])*h[g]
__global__ __launch_bounds__(320) void gather_kernel(
    const float* __restrict__ hcur, const ushort* __restrict__ hUb,
    const ushort* __restrict__ xproj, const int* __restrict__ graph,
    float* __restrict__ sumh, ushort* __restrict__ sghb)
{
    __shared__ int gsh[8][NEI];
    const int t = threadIdx.x;
    if (t < 64) {
        const int n = blockIdx.x * 8 + (t >> 3);
        gsh[t >> 3][t & 7] = graph[(size_t)n * NEI + (t & 7)];
    }
    __syncthreads();

    const int nl = t / 40;
    const int n  = blockIdx.x * 8 + nl;
    const int c4 = (t % 40) * 4;

    const ushort4 xr4 = *reinterpret_cast<const ushort4*>(&xproj[(size_t)n * 480 + 160 + c4]);
    const float xx = bf2f(xr4.x), xy = bf2f(xr4.y), xz_ = bf2f(xr4.z), xw = bf2f(xr4.w);

    float sx = 0.f, sy = 0.f, sz = 0.f, sw = 0.f;
    float gx = 0.f, gy = 0.f, gz = 0.f, gw = 0.f;

    #pragma unroll
    for (int k = 0; k < NEI; ++k) {
        const int g = gsh[nl][k];
        const float4  hv = *reinterpret_cast<const float4*>(&hcur[(size_t)g * HID + c4]);
        const ushort4 hu = *reinterpret_cast<const ushort4*>(&hUb[(size_t)g * HID + c4]);
        const float rx = sigf(xx + bf2f(hu.x));
        const float ry = sigf(xy + bf2f(hu.y));
        const float rz = sigf(xz_ + bf2f(hu.z));
        const float rw = sigf(xw + bf2f(hu.w));
        sx += hv.x; sy += hv.y; sz += hv.z; sw += hv.w;
        gx = fmaf(rx, hv.x, gx);
        gy = fmaf(ry, hv.y, gy);
        gz = fmaf(rz, hv.z, gz);
        gw = fmaf(rw, hv.w, gw);
    }
    *reinterpret_cast<float4*>(&sumh[(size_t)n * HID + c4]) = make_float4(sx, sy, sz, sw);
    ushort4 go;
    go.x = f2bf(gx); go.y = f2bf(gy); go.z = f2bf(gz); go.w = f2bf(gw);
    *reinterpret_cast<ushort4*>(&sghb[(size_t)n * HID + c4]) = go;
}

// ---------------- fused: z-GEMM + h-GEMM + gate update -> h_out
__global__ __launch_bounds__(256, 3) void gemm_zh_update(
    const float* __restrict__ sumh, const ushort* __restrict__ sghb,
    const ushort* __restrict__ wpack, const ushort* __restrict__ xproj,
    float* __restrict__ out, int M)
{
    __shared__ ushort Az[64 * AST];   // bf16(sumh)
    __shared__ ushort Ag[64 * AST];   // sgh (already bf16)
    const int t = threadIdx.x, m0 = blockIdx.x * 64;

    for (int idx = t; idx < 64 * 40; idx += 256) {
        const int m = idx / 40, k4 = (idx % 40) * 4;
        float4 v = make_float4(0.f, 0.f, 0.f, 0.f);
        if (m0 + m < M) v = *reinterpret_cast<const float4*>(&sumh[(size_t)(m0 + m) * HID + k4]);
        ushort4 hv;
        hv.x = f2bf(v.x); hv.y = f2bf(v.y); hv.z = f2bf(v.z); hv.w = f2bf(v.w);
        *reinterpret_cast<ushort4*>(&Az[m * AST + k4]) = hv;
    }
    for (int idx = t; idx < 64 * 20; idx += 256) {
        const int m = idx / 20, c8 = (idx % 20) * 8;
        short8 v = (short8){0,0,0,0,0,0,0,0};
        if (m0 + m < M) v = *reinterpret_cast<const short8*>(&sghb[(size_t)(m0 + m) * HID + c8]);
        *reinterpret_cast<short8*>(&Ag[m * AST + c8]) = v;
    }
    __syncthreads();

    const int w = t >> 6, l = t & 63;
    const int ar = (w << 4) + (l & 15);
    const int kg = (l >> 4) << 3;

    f32x4 accz[10], acch[10];
    #pragma unroll
    for (int nt = 0; nt < 10; ++nt) {
        accz[nt] = (f32x4){0.f, 0.f, 0.f, 0.f};
        acch[nt] = (f32x4){0.f, 0.f, 0.f, 0.f};
    }

    const short8* ZH = reinterpret_cast<const short8*>(wpack + WPZH_BASE);
    const short8* ZL = reinterpret_cast<const short8*>(wpack + WPZH_BASE + 25600);
    const short8* HH = reinterpret_cast<const short8*>(wpack + WPHH_BASE);
    const short8* HL = reinterpret_cast<const short8*>(wpack + WPHH_BASE + 25600);

    #pragma unroll
    for (int ks = 0; ks < 5; ++ks) {
        const short8 az = *reinterpret_cast<const short8*>(&Az[ar * AST + ks * 32 + kg]);
        const short8 ag = *reinterpret_cast<const short8*>(&Ag[ar * AST + ks * 32 + kg]);
        #pragma unroll
        for (int nt = 0; nt < 10; ++nt) {
            const int bi = (nt * 5 + ks) * 64 + l;
            accz[nt] = __builtin_amdgcn_mfma_f32_16x16x32_bf16(az, ZH[bi], accz[nt], 0, 0, 0);
            accz[nt] = __builtin_amdgcn_mfma_f32_16x16x32_bf16(az, ZL[bi], accz[nt], 0, 0, 0);
            acch[nt] = __builtin_amdgcn_mfma_f32_16x16x32_bf16(ag, HH[bi], acch[nt], 0, 0, 0);
            acch[nt] = __builtin_amdgcn_mfma_f32_16x16x32_bf16(ag, HL[bi], acch[nt], 0, 0, 0);
        }
    }

    const int r0 = m0 + (w << 4) + ((l >> 4) << 2);
    const int cb = l & 15;
    #pragma unroll
    for (int nt = 0; nt < 10; ++nt) {
        const int col = nt * 16 + cb;
        #pragma unroll
        for (int r = 0; r < 4; ++r) {
            const int m = r0 + r;
            if (m < M) {
                const float z = sigf(accz[nt][r] + bf2f(xproj[(size_t)m * 480 + col]));
                const float p = tanhfast(acch[nt][r] + bf2f(xproj[(size_t)m * 480 + 320 + col]));
                const float s = sumh[(size_t)m * HID + col];
                float v = (1.f - z) * s + z * p;
                if (m == 0) v = 0.f;
                out[(size_t)m * HID + col] = v;
            }
        }
    }
}

extern "C" void kernel_launch(void* const* d_in, const int* in_sizes, int n_in,
                              void* d_out, int out_size, void* d_ws, size_t ws_size,
                              hipStream_t stream)
{
    const float* h0   = (const float*)d_in[0];
    const float* x    = (const float*)d_in[1];
    const int*   grf  = (const int*)  d_in[2];
    const float* Wz_w = (const float*)d_in[3];
    const float* Wz_b = (const float*)d_in[4];
    const float* Wr_w = (const float*)d_in[5];
    const float* Ur_w = (const float*)d_in[6];
    const float* Ur_b = (const float*)d_in[7];
    const float* Wh_w = (const float*)d_in[8];
    const float* Wh_b = (const float*)d_in[9];
    float* out = (float*)d_out;

    const size_t per = (size_t)NM * HID;
    float*  sumh  = (float*)d_ws;                 // 32 MB
    ushort* sghb  = (ushort*)(sumh + per);        // 16 MB
    ushort* hUb   = sghb + per;                   // 16 MB
    ushort* xproj = hUb + per;                    // 48 MB
    ushort* wpack = xproj + per * 3;              // 0.6 MB

    const dim3 gb((NM + 63) / 64), gt(256);       // 782 blocks
    const dim3 sb(NM / 8), st(320);               // 6250 blocks

    pack_weights<<<6, 256, 0, stream>>>(Wz_w, Wr_w, Ur_w, Wh_w, wpack);
    xproj_gemm<<<gb, gt, 0, stream>>>(x, wpack, Wz_b, Wh_b, xproj, NM);

    const float* hcur = h0;
    for (int it = 0; it < 3; ++it) {
        gemm_hU<<<gb, gt, 0, stream>>>(hcur, wpack, Ur_b, hUb, NM);
        gather_kernel<<<sb, st, 0, stream>>>(hcur, hUb, xproj, grf, sumh, sghb);
        gemm_zh_update<<<gb, gt, 0, stream>>>(sumh, sghb, wpack, xproj, out, NM);
        hcur = out;
    }
}

// Round 4
// 432.771 us; speedup vs baseline: 4.6879x; 1.4854x over previous
//
#include <hip/hip_runtime.h>
#include <cstddef>
#include <cstdint>

#define NM  50000
#define HID 160
#define NEI 8
#define AST 168   // LDS row stride (ushorts): 336B rows, conflict-benign b128 reads

// packed-weight offsets (ushort units)
#define WPX_HI    0        // [30nt][5ks][64l][8] x-proj weights (Wzx, Wr, Whx)
#define WPX_LO    76800
#define WPU_BASE  153600   // Ur   hi, lo at +25600
#define WPZH_BASE 204800   // Wzh  hi, lo at +25600
#define WPHH_BASE 256000   // Whh  hi, lo at +25600
#define WPACK_TOTAL 307200

typedef __attribute__((ext_vector_type(8))) short  short8;
typedef __attribute__((ext_vector_type(4))) float  f32x4;

__device__ __forceinline__ ushort f2bf(float f) {
    union { float f; uint32_t u; } v; v.f = f;
    const uint32_t r = v.u + 0x7fffu + ((v.u >> 16) & 1u);   // RNE
    return (ushort)(r >> 16);
}
__device__ __forceinline__ float bf2f(ushort h) {
    union { uint32_t u; float f; } v; v.u = ((uint32_t)h) << 16;
    return v.f;
}
__device__ __forceinline__ float sigf(float v)     { return 1.f / (1.f + __expf(-v)); }
__device__ __forceinline__ float tanhfast(float v) { return 2.f / (1.f + __expf(-2.f * v)) - 1.f; }

// ---------------- weight pre-pack into MFMA B-fragment-linear order (hi/lo bf16)
__global__ __launch_bounds__(256) void pack_weights(
    const float* __restrict__ Wz, const float* __restrict__ Wr,
    const float* __restrict__ Ur, const float* __restrict__ Wh,
    ushort* __restrict__ dst)
{
    const float* src; int off, stride, ntb = 0; ushort *hi, *lo;
    switch (blockIdx.x) {
        case 0:  src = Wz; off = 0;   stride = 320; hi = dst + WPX_HI;    lo = dst + WPX_LO;  ntb = 0;  break;
        case 1:  src = Wr; off = 0;   stride = 160; hi = dst + WPX_HI;    lo = dst + WPX_LO;  ntb = 10; break;
        case 2:  src = Wh; off = 0;   stride = 320; hi = dst + WPX_HI;    lo = dst + WPX_LO;  ntb = 20; break;
        case 3:  src = Ur; off = 0;   stride = 160; hi = dst + WPU_BASE;  lo = hi + 25600;    break;
        case 4:  src = Wz; off = 160; stride = 320; hi = dst + WPZH_BASE; lo = hi + 25600;    break;
        default: src = Wh; off = 160; stride = 320; hi = dst + WPHH_BASE; lo = hi + 25600;    break;
    }
    const int t = threadIdx.x, l = t & 63;
    for (int tile = t >> 6; tile < 50; tile += 4) {
        const int ntl = tile / 5, ks = tile % 5;
        const int n = ntl * 16 + (l & 15);
        const int k = ks * 32 + (l >> 4) * 8;
        const float* s = &src[(size_t)n * stride + off + k];
        const size_t o = ((size_t)((ntb + ntl) * 5 + ks) * 64 + l) * 8;
        #pragma unroll
        for (int j = 0; j < 8; ++j) {
            const float a  = s[j];
            const ushort hb = f2bf(a);
            hi[o + j] = hb;
            lo[o + j] = f2bf(a - bf2f(hb));
        }
    }
}

// ---------------- x projections, grid (782,3): y picks {xz, xr, xh} chunk
__global__ __launch_bounds__(256) void xproj_gemm(
    const float* __restrict__ x, const ushort* __restrict__ wpack,
    const float* __restrict__ Wz_b, const float* __restrict__ Wh_b,
    ushort* __restrict__ xproj, int M)
{
    __shared__ ushort As[64 * AST];
    const int t = threadIdx.x, m0 = blockIdx.x * 64, cy = blockIdx.y;

    for (int idx = t; idx < 64 * 40; idx += 256) {
        const int m = idx / 40, k4 = (idx % 40) * 4;
        float4 v = make_float4(0.f, 0.f, 0.f, 0.f);
        if (m0 + m < M) v = *reinterpret_cast<const float4*>(&x[(size_t)(m0 + m) * HID + k4]);
        ushort4 hv;
        hv.x = f2bf(v.x); hv.y = f2bf(v.y); hv.z = f2bf(v.z); hv.w = f2bf(v.w);
        *reinterpret_cast<ushort4*>(&As[m * AST + k4]) = hv;
    }
    __syncthreads();

    const int w = t >> 6, l = t & 63;
    const int ar = (w << 4) + (l & 15);
    const int kg = (l >> 4) << 3;

    f32x4 acc[10];
    #pragma unroll
    for (int nt = 0; nt < 10; ++nt) acc[nt] = (f32x4){0.f, 0.f, 0.f, 0.f};

    const short8* WH = reinterpret_cast<const short8*>(wpack + WPX_HI + cy * 25600);
    const short8* WL = reinterpret_cast<const short8*>(wpack + WPX_LO + cy * 25600);

    #pragma unroll
    for (int ks = 0; ks < 5; ++ks) {
        const short8 a = *reinterpret_cast<const short8*>(&As[ar * AST + ks * 32 + kg]);
        #pragma unroll
        for (int nt = 0; nt < 10; ++nt) {
            const short8 bh = WH[(nt * 5 + ks) * 64 + l];
            const short8 bl = WL[(nt * 5 + ks) * 64 + l];
            acc[nt] = __builtin_amdgcn_mfma_f32_16x16x32_bf16(a, bh, acc[nt], 0, 0, 0);
            acc[nt] = __builtin_amdgcn_mfma_f32_16x16x32_bf16(a, bl, acc[nt], 0, 0, 0);
        }
    }
    __syncthreads();

    // stage result to LDS (reuse As) for coalesced bf16 stores
    const int r0l = (w << 4) + ((l >> 4) << 2);
    const int cb = l & 15;
    const float* bias = (cy == 0) ? Wz_b : (cy == 2) ? Wh_b : nullptr;
    #pragma unroll
    for (int nt = 0; nt < 10; ++nt) {
        const int col = nt * 16 + cb;
        const float b = bias ? bias[col] : 0.f;
        #pragma unroll
        for (int r = 0; r < 4; ++r)
            As[(r0l + r) * AST + col] = f2bf(acc[nt][r] + b);
    }
    __syncthreads();
    for (int idx = t; idx < 64 * 20; idx += 256) {
        const int m = idx / 20, g8 = (idx % 20) * 8;
        if (m0 + m < M)
            *reinterpret_cast<short8*>(&xproj[(size_t)(m0 + m) * 480 + cy * 160 + g8]) =
                *reinterpret_cast<const short8*>(&As[m * AST + g8]);
    }
}

// ---------------- hU0: hh[n] = [bf16(h0) | bf16(h0 @ Ur^T + Ur_b)]
__global__ __launch_bounds__(256, 3) void hU0_gemm(
    const float* __restrict__ h0, const ushort* __restrict__ wpack,
    const float* __restrict__ Ur_b, ushort* __restrict__ hh, int M)
{
    __shared__ ushort As[64 * AST];
    __shared__ ushort Hu[64 * AST];
    const int t = threadIdx.x, m0 = blockIdx.x * 64;

    for (int idx = t; idx < 64 * 40; idx += 256) {
        const int m = idx / 40, k4 = (idx % 40) * 4;
        float4 v = make_float4(0.f, 0.f, 0.f, 0.f);
        if (m0 + m < M) v = *reinterpret_cast<const float4*>(&h0[(size_t)(m0 + m) * HID + k4]);
        ushort4 hv;
        hv.x = f2bf(v.x); hv.y = f2bf(v.y); hv.z = f2bf(v.z); hv.w = f2bf(v.w);
        *reinterpret_cast<ushort4*>(&As[m * AST + k4]) = hv;
    }
    __syncthreads();

    // coalesced h-half stores
    for (int idx = t; idx < 64 * 20; idx += 256) {
        const int m = idx / 20, g8 = (idx % 20) * 8;
        if (m0 + m < M)
            *reinterpret_cast<short8*>(&hh[(size_t)(m0 + m) * 320 + g8]) =
                *reinterpret_cast<const short8*>(&As[m * AST + g8]);
    }

    const int w = t >> 6, l = t & 63;
    const int ar = (w << 4) + (l & 15);
    const int kg = (l >> 4) << 3;

    f32x4 acc[10];
    #pragma unroll
    for (int nt = 0; nt < 10; ++nt) acc[nt] = (f32x4){0.f, 0.f, 0.f, 0.f};

    const short8* WH = reinterpret_cast<const short8*>(wpack + WPU_BASE);
    const short8* WL = reinterpret_cast<const short8*>(wpack + WPU_BASE + 25600);

    #pragma unroll
    for (int ks = 0; ks < 5; ++ks) {
        const short8 a = *reinterpret_cast<const short8*>(&As[ar * AST + ks * 32 + kg]);
        #pragma unroll
        for (int nt = 0; nt < 10; ++nt) {
            const short8 bh = WH[(nt * 5 + ks) * 64 + l];
            const short8 bl = WL[(nt * 5 + ks) * 64 + l];
            acc[nt] = __builtin_amdgcn_mfma_f32_16x16x32_bf16(a, bh, acc[nt], 0, 0, 0);
            acc[nt] = __builtin_amdgcn_mfma_f32_16x16x32_bf16(a, bl, acc[nt], 0, 0, 0);
        }
    }

    const int r0l = (w << 4) + ((l >> 4) << 2);
    const int cb = l & 15;
    #pragma unroll
    for (int nt = 0; nt < 10; ++nt) {
        const int col = nt * 16 + cb;
        const float b = Ur_b[col];
        #pragma unroll
        for (int r = 0; r < 4; ++r)
            Hu[(r0l + r) * AST + col] = f2bf(acc[nt][r] + b);
    }
    __syncthreads();
    for (int idx = t; idx < 64 * 20; idx += 256) {
        const int m = idx / 20, g8 = (idx % 20) * 8;
        if (m0 + m < M)
            *reinterpret_cast<short8*>(&hh[(size_t)(m0 + m) * 320 + 160 + g8]) =
                *reinterpret_cast<const short8*>(&Hu[m * AST + g8]);
    }
}

// ---------------- fused iteration: gather -> zh-GEMM -> update -> (Ur-GEMM for next)
__global__ __launch_bounds__(256, 3) void fused_iter(
    const ushort* __restrict__ hh,      // [N][320] bf16: h | hU
    const ushort* __restrict__ xproj,   // [N][480] bf16: xz | xr | xh
    const int*    __restrict__ graph,
    const ushort* __restrict__ wpack,
    const float*  __restrict__ Ur_b,
    float*  __restrict__ out,           // [N][160] f32
    ushort* __restrict__ hh_next,       // [N][320] bf16 (ping-pong, != hh)
    int do_next, int M)
{
    __shared__ ushort Az[64 * AST];     // bf16 sumh, later bf16 h_out
    __shared__ ushort Ag[64 * AST];     // bf16 sgh,  later bf16 hU_out
    __shared__ int    gl[64][NEI];
    const int t = threadIdx.x, m0 = blockIdx.x * 64;

    for (int idx = t; idx < 64 * NEI; idx += 256) {
        const int r = idx >> 3, k = idx & 7;
        gl[r][k] = (m0 + r < M) ? graph[(size_t)(m0 + r) * NEI + k] : 0;
    }
    __syncthreads();

    // gather phase: 64 rows x 20 groups of 8 elems
    for (int idx = t; idx < 1280; idx += 256) {
        const int r = idx / 20, g8 = (idx % 20) * 8;
        const int n = m0 + r;
        float s[8], g[8];
        #pragma unroll
        for (int j = 0; j < 8; ++j) { s[j] = 0.f; g[j] = 0.f; }
        if (n < M) {
            const short8 xr8 = *reinterpret_cast<const short8*>(&xproj[(size_t)n * 480 + 160 + g8]);
            #pragma unroll
            for (int k = 0; k < NEI; ++k) {
                const int gg = gl[r][k];
                const short8 hv = *reinterpret_cast<const short8*>(&hh[(size_t)gg * 320 + g8]);
                const short8 hu = *reinterpret_cast<const short8*>(&hh[(size_t)gg * 320 + 160 + g8]);
                #pragma unroll
                for (int j = 0; j < 8; ++j) {
                    const float h = bf2f((ushort)hv[j]);
                    const float rg = sigf(bf2f((ushort)xr8[j]) + bf2f((ushort)hu[j]));
                    s[j] += h;
                    g[j] = fmaf(rg, h, g[j]);
                }
            }
        }
        short8 sv, gv;
        #pragma unroll
        for (int j = 0; j < 8; ++j) { sv[j] = (short)f2bf(s[j]); gv[j] = (short)f2bf(g[j]); }
        *reinterpret_cast<short8*>(&Az[r * AST + g8]) = sv;
        *reinterpret_cast<short8*>(&Ag[r * AST + g8]) = gv;
    }
    __syncthreads();

    const int w = t >> 6, l = t & 63;
    const int ar = (w << 4) + (l & 15);
    const int kg = (l >> 4) << 3;

    f32x4 accz[10], acch[10];
    #pragma unroll
    for (int nt = 0; nt < 10; ++nt) {
        accz[nt] = (f32x4){0.f, 0.f, 0.f, 0.f};
        acch[nt] = (f32x4){0.f, 0.f, 0.f, 0.f};
    }

    {
        const short8* ZH = reinterpret_cast<const short8*>(wpack + WPZH_BASE);
        const short8* ZL = reinterpret_cast<const short8*>(wpack + WPZH_BASE + 25600);
        const short8* HH = reinterpret_cast<const short8*>(wpack + WPHH_BASE);
        const short8* HL = reinterpret_cast<const short8*>(wpack + WPHH_BASE + 25600);
        #pragma unroll
        for (int ks = 0; ks < 5; ++ks) {
            const short8 az = *reinterpret_cast<const short8*>(&Az[ar * AST + ks * 32 + kg]);
            const short8 ag = *reinterpret_cast<const short8*>(&Ag[ar * AST + ks * 32 + kg]);
            #pragma unroll
            for (int nt = 0; nt < 10; ++nt) {
                const int bi = (nt * 5 + ks) * 64 + l;
                accz[nt] = __builtin_amdgcn_mfma_f32_16x16x32_bf16(az, ZH[bi], accz[nt], 0, 0, 0);
                accz[nt] = __builtin_amdgcn_mfma_f32_16x16x32_bf16(az, ZL[bi], accz[nt], 0, 0, 0);
                acch[nt] = __builtin_amdgcn_mfma_f32_16x16x32_bf16(ag, HH[bi], acch[nt], 0, 0, 0);
                acch[nt] = __builtin_amdgcn_mfma_f32_16x16x32_bf16(ag, HL[bi], acch[nt], 0, 0, 0);
            }
        }
    }

    // epilogue: v = (1-z)*sumh + z*tanh(.)  (v kept in accz for the Ur tail)
    const int r0l = (w << 4) + ((l >> 4) << 2);
    const int cb = l & 15;
    #pragma unroll
    for (int nt = 0; nt < 10; ++nt) {
        const int col = nt * 16 + cb;
        #pragma unroll
        for (int r = 0; r < 4; ++r) {
            const int m = m0 + r0l + r;
            float v = 0.f;
            if (m < M) {
                const float z = sigf(accz[nt][r] + bf2f(xproj[(size_t)m * 480 + col]));
                const float p = tanhfast(acch[nt][r] + bf2f(xproj[(size_t)m * 480 + 320 + col]));
                const float s = bf2f(Az[(r0l + r) * AST + col]);
                v = (1.f - z) * s + z * p;
                if (m == 0) v = 0.f;
                out[(size_t)m * HID + col] = v;
            }
            accz[nt][r] = v;
        }
    }

    if (!do_next) return;

    __syncthreads();   // all Az(sumh) reads done
    #pragma unroll
    for (int nt = 0; nt < 10; ++nt) {
        const int col = nt * 16 + cb;
        #pragma unroll
        for (int r = 0; r < 4; ++r)
            Az[(r0l + r) * AST + col] = f2bf(accz[nt][r]);   // bf16 h_out
    }
    __syncthreads();

    // coalesced h-half stores + Ur-GEMM from Az
    for (int idx = t; idx < 64 * 20; idx += 256) {
        const int m = idx / 20, g8 = (idx % 20) * 8;
        if (m0 + m < M)
            *reinterpret_cast<short8*>(&hh_next[(size_t)(m0 + m) * 320 + g8]) =
                *reinterpret_cast<const short8*>(&Az[m * AST + g8]);
    }

    #pragma unroll
    for (int nt = 0; nt < 10; ++nt) acch[nt] = (f32x4){0.f, 0.f, 0.f, 0.f};
    {
        const short8* WH = reinterpret_cast<const short8*>(wpack + WPU_BASE);
        const short8* WL = reinterpret_cast<const short8*>(wpack + WPU_BASE + 25600);
        #pragma unroll
        for (int ks = 0; ks < 5; ++ks) {
            const short8 a = *reinterpret_cast<const short8*>(&Az[ar * AST + ks * 32 + kg]);
            #pragma unroll
            for (int nt = 0; nt < 10; ++nt) {
                const int bi = (nt * 5 + ks) * 64 + l;
                acch[nt] = __builtin_amdgcn_mfma_f32_16x16x32_bf16(a, WH[bi], acch[nt], 0, 0, 0);
                acch[nt] = __builtin_amdgcn_mfma_f32_16x16x32_bf16(a, WL[bi], acch[nt], 0, 0, 0);
            }
        }
    }
    #pragma unroll
    for (int nt = 0; nt < 10; ++nt) {
        const int col = nt * 16 + cb;
        const float b = Ur_b[col];
        #pragma unroll
        for (int r = 0; r < 4; ++r)
            Ag[(r0l + r) * AST + col] = f2bf(acch[nt][r] + b);
    }
    __syncthreads();
    for (int idx = t; idx < 64 * 20; idx += 256) {
        const int m = idx / 20, g8 = (idx % 20) * 8;
        if (m0 + m < M)
            *reinterpret_cast<short8*>(&hh_next[(size_t)(m0 + m) * 320 + 160 + g8]) =
                *reinterpret_cast<const short8*>(&Ag[m * AST + g8]);
    }
}

extern "C" void kernel_launch(void* const* d_in, const int* in_sizes, int n_in,
                              void* d_out, int out_size, void* d_ws, size_t ws_size,
                              hipStream_t stream)
{
    const float* h0   = (const float*)d_in[0];
    const float* x    = (const float*)d_in[1];
    const int*   grf  = (const int*)  d_in[2];
    const float* Wz_w = (const float*)d_in[3];
    const float* Wz_b = (const float*)d_in[4];
    const float* Wr_w = (const float*)d_in[5];
    const float* Ur_w = (const float*)d_in[6];
    const float* Ur_b = (const float*)d_in[7];
    const float* Wh_w = (const float*)d_in[8];
    const float* Wh_b = (const float*)d_in[9];
    float* out = (float*)d_out;

    const size_t per = (size_t)NM * HID;
    ushort* xproj = (ushort*)d_ws;            // 48 MB
    ushort* hh_a  = xproj + per * 3;          // 32 MB
    ushort* hh_b  = hh_a + per * 2;           // 32 MB
    ushort* wpack = hh_b + per * 2;           // 0.6 MB

    const dim3 gb((NM + 63) / 64), gt(256);   // 782 blocks

    pack_weights<<<6, 256, 0, stream>>>(Wz_w, Wr_w, Ur_w, Wh_w, wpack);
    xproj_gemm<<<dim3(gb.x, 3), gt, 0, stream>>>(x, wpack, Wz_b, Wh_b, xproj, NM);
    hU0_gemm<<<gb, gt, 0, stream>>>(h0, wpack, Ur_b, hh_a, NM);

    fused_iter<<<gb, gt, 0, stream>>>(hh_a, xproj, grf, wpack, Ur_b, out, hh_b, 1, NM);
    fused_iter<<<gb, gt, 0, stream>>>(hh_b, xproj, grf, wpack, Ur_b, out, hh_a, 1, NM);
    fused_iter<<<gb, gt, 0, stream>>>(hh_a, xproj, grf, wpack, Ur_b, out, hh_b, 0, NM);
}